// Round 6
// baseline (213.811 us; speedup 1.0000x reference)
//
#include <hip/hip_runtime.h>
#include <stdint.h>

typedef __bf16 bf16x8 __attribute__((ext_vector_type(8)));
typedef float  f32x4  __attribute__((ext_vector_type(4)));
typedef float  float4v __attribute__((ext_vector_type(4)));
typedef short  short8 __attribute__((ext_vector_type(8)));
typedef short  short4v __attribute__((ext_vector_type(4)));

static constexpr int Mtot = 8192;        // B*S
static constexpr int Ntot = 2048;        // D_OUT
static constexpr int Ktot = 2048;        // D_IN
static constexpr int NE = 8, NR = 16;
static constexpr int R2 = NE * NR;       // 128 stacked rank
static constexpr float SCALING = 16.0f / 16.0f;

__device__ __forceinline__ ushort f2bf(float f) {
  union { float f; uint32_t u; } v; v.f = f;
  uint32_t r = (v.u + 0x7FFFu + ((v.u >> 16) & 1u)) >> 16;
  return (ushort)r;
}

__device__ __forceinline__ void lds16(const void* g, void* l) {
  __builtin_amdgcn_global_load_lds(
      (const __attribute__((address_space(1))) void*)g,
      (__attribute__((address_space(3))) void*)l, 16, 0, 0);
}

// ---------- kernel 1: cvt x -> bf16 (dense) + build Abt/Bst bf16 ----------
// blocks [0,8192): cvt x.  [8192,8200): Abt[d][i]=bf16(lA[i][d]).
// [8200,8208): Bst[o][e*16+r]=bf16(lB[e][o][r]*mask_e*SCALING).
__global__ __launch_bounds__(256) void k_prep(const float* __restrict__ x,
                                              ushort* __restrict__ xb,
                                              const float* __restrict__ lA,   // [E][R][K] = [128][2048]
                                              const float* __restrict__ lB,   // [E][N][R]
                                              const int* __restrict__ mask,   // [E]
                                              ushort* __restrict__ Abt,       // [2048][128]
                                              ushort* __restrict__ Bst) {     // [2048][128]
  int tid = threadIdx.x;
  if (blockIdx.x < 8192) {
    size_t base = (size_t)blockIdx.x * 2048;
    int t4 = tid * 4;
    float4v a = *reinterpret_cast<const float4v*>(x + base + t4);
    float4v c = *reinterpret_cast<const float4v*>(x + base + 1024 + t4);
    short4v s0, s1;
    s0[0] = (short)f2bf(a[0]); s0[1] = (short)f2bf(a[1]);
    s0[2] = (short)f2bf(a[2]); s0[3] = (short)f2bf(a[3]);
    s1[0] = (short)f2bf(c[0]); s1[1] = (short)f2bf(c[1]);
    s1[2] = (short)f2bf(c[2]); s1[3] = (short)f2bf(c[3]);
    *reinterpret_cast<short4v*>(xb + base + t4) = s0;
    *reinterpret_cast<short4v*>(xb + base + 1024 + t4) = s1;
  } else if (blockIdx.x < 8200) {
    // Abt: thread owns column d of lA; reads are wave-coalesced per i.
    int d = (blockIdx.x - 8192) * 256 + tid;
    short8 buf[16];
    #pragma unroll 8
    for (int i = 0; i < R2; ++i)
      ((short*)buf)[i] = (short)f2bf(lA[(size_t)i * Ktot + d]);
    #pragma unroll
    for (int q = 0; q < 16; ++q)
      *reinterpret_cast<short8*>(Abt + (size_t)d * R2 + q * 8) = buf[q];
  } else {
    // Bst: thread owns row o; mask*scaling folded in.
    int o = (blockIdx.x - 8200) * 256 + tid;
    short8 buf[16];
    #pragma unroll
    for (int e = 0; e < NE; ++e) {
      float m = (mask[e] != 0) ? SCALING : 0.0f;
      #pragma unroll
      for (int rg = 0; rg < 4; ++rg) {
        float4v v = *reinterpret_cast<const float4v*>(lB + ((size_t)e * Ntot + o) * NR + rg * 4);
        ((short*)buf)[e * 16 + rg * 4 + 0] = (short)f2bf(v[0] * m);
        ((short*)buf)[e * 16 + rg * 4 + 1] = (short)f2bf(v[1] * m);
        ((short*)buf)[e * 16 + rg * 4 + 2] = (short)f2bf(v[2] * m);
        ((short*)buf)[e * 16 + rg * 4 + 3] = (short)f2bf(v[3] * m);
      }
    }
    #pragma unroll
    for (int q = 0; q < 16; ++q)
      *reinterpret_cast<short8*>(Bst + (size_t)o * R2 + q * 8) = buf[q];
  }
}

// ---------- kernel 2: W_eff via MFMA: Wb = bf16(W + Bst @ Abt^T) ----------
// 128x128 tile, 4 waves (2x2), K=128 single-shot in LDS, XOR-swizzled.
__global__ __launch_bounds__(256) void k_weff_mfma(const ushort* __restrict__ Bst, // [2048][128]
                                                   const ushort* __restrict__ Abt, // [2048][128]
                                                   const float* __restrict__ W,    // [2048][2048]
                                                   ushort* __restrict__ Wb) {      // [2048][2048]
  __shared__ __align__(128) char sA[32768];  // Bst tile: 128 rows(o) x 256B
  __shared__ __align__(128) char sB[32768];  // Abt tile: 128 rows(d) x 256B
  int bid = blockIdx.x;
  int o0 = (bid >> 4) * 128;
  int d0 = (bid & 15) * 128;
  int tid = threadIdx.x, w = tid >> 6, l = tid & 63;

  // stage: wave w covers rows w*32+j*4+(l>>4), slot l&15; linear LDS dest,
  // source col XOR'd with ((row&7)<<4)  (both-sides rule #21).
  int srow = w * 32 + (l >> 4);
  int scolb = (l & 15) * 16;
  #pragma unroll
  for (int j = 0; j < 8; ++j) {
    int row = srow + j * 4;
    int colb = scolb ^ ((row & 7) << 4);
    lds16((const char*)Bst + (size_t)(o0 + row) * 256 + colb, sA + w * 8192 + j * 1024);
    lds16((const char*)Abt + (size_t)(d0 + row) * 256 + colb, sB + w * 8192 + j * 1024);
  }
  __syncthreads();

  int wr = w >> 1, wc = w & 1;     // wave -> 64x64 out sub-tile
  int fr = l & 15;
  int fk16 = (l >> 4) * 16;
  int xm = (fr & 7) << 4;

  f32x4 acc[4][4];
  #pragma unroll
  for (int i = 0; i < 4; ++i)
    #pragma unroll
    for (int j = 0; j < 4; ++j) acc[i][j] = f32x4{0.f, 0.f, 0.f, 0.f};

  #pragma unroll
  for (int ks = 0; ks < 4; ++ks) {
    int kx = (ks * 64 + fk16) ^ xm;
    bf16x8 aF[4], bF[4];
    #pragma unroll
    for (int mi = 0; mi < 4; ++mi)
      aF[mi] = *reinterpret_cast<const bf16x8*>(sA + (wr * 64 + mi * 16 + fr) * 256 + kx);
    #pragma unroll
    for (int nj = 0; nj < 4; ++nj)
      bF[nj] = *reinterpret_cast<const bf16x8*>(sB + (wc * 64 + nj * 16 + fr) * 256 + kx);
    #pragma unroll
    for (int mi = 0; mi < 4; ++mi)
      #pragma unroll
      for (int nj = 0; nj < 4; ++nj)
        acc[mi][nj] = __builtin_amdgcn_mfma_f32_16x16x32_bf16(aF[mi], bF[nj], acc[mi][nj], 0, 0, 0);
  }

  // epilogue: Wb[row][col] = bf16(W[row][col] + acc); C/D map col=lane&15.
  int rr4 = (l >> 4) * 4;
  #pragma unroll
  for (int nj = 0; nj < 4; ++nj) {
    int col = d0 + wc * 64 + nj * 16 + fr;
    #pragma unroll
    for (int mi = 0; mi < 4; ++mi) {
      int row0 = o0 + wr * 64 + mi * 16 + rr4;
      #pragma unroll
      for (int r = 0; r < 4; ++r) {
        float v = acc[mi][nj][r] + W[(size_t)(row0 + r) * Ktot + col];
        Wb[(size_t)(row0 + r) * Ktot + col] = f2bf(v);
      }
    }
  }
}

// ---------- kernel 3: 256x256-tile 8-wave GEMM ----------
// Same proven sync skeleton as R5 (ring-4, prefetch-2, vmcnt(4)+barrier per
// tile). Change: mid-tile barriers removed (they were schedule-shaping only);
// tile body software-pipelined: bF prologue, per-mi {read aF[mi+2], 4 MFMA}.
__global__ __launch_bounds__(512, 2) void k_gemm256(const ushort* __restrict__ Xb,
                                                    const ushort* __restrict__ Wb,
                                                    const float* __restrict__ bias,
                                                    float* __restrict__ out) {
  constexpr int BK = 32;
  constexpr int NT = Ktot / BK;           // 64
  constexpr int NTN = Ntot / 256;         // 8
  __shared__ __align__(128) char smem[4 * 32768];   // ring: 4 x (A 16KB + B 16KB)

  int nwg = gridDim.x;                    // 256, %8==0
  int orig = blockIdx.x;
  int wg = (orig & 7) * (nwg >> 3) + (orig >> 3);
  int mBase = (wg / NTN) * 256;
  int nBase = (wg % NTN) * 256;

  int tid = threadIdx.x;
  int w = tid >> 6, l = tid & 63;
  int wr = w >> 2, wc = w & 3;            // wave -> 128x64 output sub-tile

  int rowOff = tid >> 2;
  int cbS = ((tid & 3) * 16) ^ (((tid >> 3) & 3) << 4);
  const char* xbB = (const char*)Xb;
  const char* wbB = (const char*)Wb;
  const char* src[4];
  src[0] = xbB + (size_t)(mBase +       rowOff) * (Ktot * 2) + cbS;  // A rows 0-127
  src[1] = xbB + (size_t)(mBase + 128 + rowOff) * (Ktot * 2) + cbS;  // A rows 128-255
  src[2] = wbB + (size_t)(nBase +       rowOff) * (Ktot * 2) + cbS;  // B rows 0-127
  src[3] = wbB + (size_t)(nBase + 128 + rowOff) * (Ktot * 2) + cbS;  // B rows 128-255
  int waveB = w * 1024;

  auto stage = [&](int bufn, int which, size_t kb) {
    lds16(src[which] + kb, smem + bufn * 32768 + which * 8192 + waveB);
  };

  int fr = l & 15;
  int fkb = (l >> 4) * 16;
  int kx = fkb ^ (((fr >> 1) & 3) << 4);
  int aRd = (wr * 128 + fr) * 64 + kx;            // + mi*1024
  int bRd = 16384 + (wc * 64 + fr) * 64 + kx;     // + nj*1024

  f32x4 acc[8][4];
  #pragma unroll
  for (int i = 0; i < 8; ++i)
    #pragma unroll
    for (int j = 0; j < 4; ++j) acc[i][j] = f32x4{0.f, 0.f, 0.f, 0.f};

  #pragma unroll
  for (int q = 0; q < 4; ++q) stage(0, q, 0);
  #pragma unroll
  for (int q = 0; q < 4; ++q) stage(1, q, 64);
  __syncthreads();

  for (int t = 0; t < NT; ++t) {
    const char* buf = smem + (t & 3) * 32768;
    const bool pref = (t + 2 < NT);
    const int bn = (t + 2) & 3;
    const size_t kb = (size_t)(t + 2) * 64;

    bf16x8 bF[4], aF[8];
    // consumption-ordered reads: LDS returns in order, so fine-grained
    // lgkmcnt lets MFMAs start as soon as their operands land.
    #pragma unroll
    for (int nj = 0; nj < 4; ++nj)
      bF[nj] = *reinterpret_cast<const bf16x8*>(buf + bRd + nj * 1024);
    aF[0] = *reinterpret_cast<const bf16x8*>(buf + aRd + 0 * 1024);
    aF[1] = *reinterpret_cast<const bf16x8*>(buf + aRd + 1 * 1024);
    if (pref) { stage(bn, 0, kb); stage(bn, 1, kb); }

    #pragma unroll
    for (int mi = 0; mi < 8; ++mi) {
      if (mi < 6)
        aF[mi + 2] = *reinterpret_cast<const bf16x8*>(buf + aRd + (mi + 2) * 1024);
      if (mi == 4 && pref) { stage(bn, 2, kb); stage(bn, 3, kb); }
      __builtin_amdgcn_s_setprio(1);
      #pragma unroll
      for (int nj = 0; nj < 4; ++nj)
        acc[mi][nj] = __builtin_amdgcn_mfma_f32_16x16x32_bf16(aF[mi], bF[nj], acc[mi][nj], 0, 0, 0);
      __builtin_amdgcn_s_setprio(0);
    }

    // correctness-critical tile boundary: tile t+1's stages must be in LDS.
    if (t + 2 < NT)      asm volatile("s_waitcnt vmcnt(4)" ::: "memory");
    else if (t + 1 < NT) asm volatile("s_waitcnt vmcnt(0)" ::: "memory");
    __builtin_amdgcn_s_barrier();
  }

  int rr = (l >> 4) * 4;
  #pragma unroll
  for (int nj = 0; nj < 4; ++nj) {
    int col = nBase + wc * 64 + nj * 16 + fr;
    float bb = bias[col];
    #pragma unroll
    for (int mi = 0; mi < 8; ++mi) {
      int row0 = mBase + wr * 128 + mi * 16 + rr;
      #pragma unroll
      for (int r = 0; r < 4; ++r)
        out[(size_t)(row0 + r) * Ntot + col] = acc[mi][nj][r] + bb;
    }
  }
}

extern "C" void kernel_launch(void* const* d_in, const int* in_sizes, int n_in,
                              void* d_out, int out_size, void* d_ws, size_t ws_size,
                              hipStream_t stream) {
  const float* x    = (const float*)d_in[0];
  const float* W    = (const float*)d_in[1];
  const float* bias = (const float*)d_in[2];
  const float* lA   = (const float*)d_in[3];
  const float* lB   = (const float*)d_in[4];
  const int*   mask = (const int*)d_in[5];
  float* out = (float*)d_out;

  ushort* xb  = (ushort*)d_ws;                      // [M][K]   bf16: 33.55 MB
  ushort* wb  = xb + (size_t)Mtot * Ktot;           // [N][K]   bf16:  8.39 MB
  ushort* abt = wb + (size_t)Ntot * Ktot;           // [K][128] bf16:  0.52 MB
  ushort* bst = abt + (size_t)Ktot * R2;            // [N][128] bf16:  0.52 MB

  k_prep<<<8192 + 8 + 8, 256, 0, stream>>>(x, xb, lA, lB, mask, abt, bst);
  k_weff_mfma<<<(Ntot / 128) * (Ktot / 128), 256, 0, stream>>>(bst, abt, W, wb);
  k_gemm256<<<(Mtot / 256) * (Ntot / 256), 512, 0, stream>>>(xb, wb, bias, out);
}

// Round 8
// 213.714 us; speedup vs baseline: 1.0005x; 1.0005x over previous
//
#include <hip/hip_runtime.h>
#include <stdint.h>

typedef __bf16 bf16x8 __attribute__((ext_vector_type(8)));
typedef float  f32x4  __attribute__((ext_vector_type(4)));
typedef float  float4v __attribute__((ext_vector_type(4)));
typedef short  short8 __attribute__((ext_vector_type(8)));
typedef short  short4v __attribute__((ext_vector_type(4)));

static constexpr int Mtot = 8192;        // B*S
static constexpr int Ntot = 2048;        // D_OUT
static constexpr int Ktot = 2048;        // D_IN
static constexpr int NE = 8, NR = 16;
static constexpr int R2 = NE * NR;       // 128 stacked rank
static constexpr float SCALING = 16.0f / 16.0f;

__device__ __forceinline__ ushort f2bf(float f) {
  union { float f; uint32_t u; } v; v.f = f;
  uint32_t r = (v.u + 0x7FFFu + ((v.u >> 16) & 1u)) >> 16;
  return (ushort)r;
}

__device__ __forceinline__ void lds16(const void* g, void* l) {
  __builtin_amdgcn_global_load_lds(
      (const __attribute__((address_space(1))) void*)g,
      (__attribute__((address_space(3))) void*)l, 16, 0, 0);
}

// ---------- kernel 1: cvt x -> bf16 (dense) + build Abt/Bst bf16 ----------
__global__ __launch_bounds__(256) void k_prep(const float* __restrict__ x,
                                              ushort* __restrict__ xb,
                                              const float* __restrict__ lA,   // [E][R][K] = [128][2048]
                                              const float* __restrict__ lB,   // [E][N][R]
                                              const int* __restrict__ mask,   // [E]
                                              ushort* __restrict__ Abt,       // [2048][128]
                                              ushort* __restrict__ Bst) {     // [2048][128]
  int tid = threadIdx.x;
  if (blockIdx.x < 8192) {
    size_t base = (size_t)blockIdx.x * 2048;
    int t4 = tid * 4;
    float4v a = *reinterpret_cast<const float4v*>(x + base + t4);
    float4v c = *reinterpret_cast<const float4v*>(x + base + 1024 + t4);
    short4v s0, s1;
    s0[0] = (short)f2bf(a[0]); s0[1] = (short)f2bf(a[1]);
    s0[2] = (short)f2bf(a[2]); s0[3] = (short)f2bf(a[3]);
    s1[0] = (short)f2bf(c[0]); s1[1] = (short)f2bf(c[1]);
    s1[2] = (short)f2bf(c[2]); s1[3] = (short)f2bf(c[3]);
    *reinterpret_cast<short4v*>(xb + base + t4) = s0;
    *reinterpret_cast<short4v*>(xb + base + 1024 + t4) = s1;
  } else if (blockIdx.x < 8200) {
    int d = (blockIdx.x - 8192) * 256 + tid;
    short8 buf[16];
    #pragma unroll 8
    for (int i = 0; i < R2; ++i)
      ((short*)buf)[i] = (short)f2bf(lA[(size_t)i * Ktot + d]);
    #pragma unroll
    for (int q = 0; q < 16; ++q)
      *reinterpret_cast<short8*>(Abt + (size_t)d * R2 + q * 8) = buf[q];
  } else {
    int o = (blockIdx.x - 8200) * 256 + tid;
    short8 buf[16];
    #pragma unroll
    for (int e = 0; e < NE; ++e) {
      float m = (mask[e] != 0) ? SCALING : 0.0f;
      #pragma unroll
      for (int rg = 0; rg < 4; ++rg) {
        float4v v = *reinterpret_cast<const float4v*>(lB + ((size_t)e * Ntot + o) * NR + rg * 4);
        ((short*)buf)[e * 16 + rg * 4 + 0] = (short)f2bf(v[0] * m);
        ((short*)buf)[e * 16 + rg * 4 + 1] = (short)f2bf(v[1] * m);
        ((short*)buf)[e * 16 + rg * 4 + 2] = (short)f2bf(v[2] * m);
        ((short*)buf)[e * 16 + rg * 4 + 3] = (short)f2bf(v[3] * m);
      }
    }
    #pragma unroll
    for (int q = 0; q < 16; ++q)
      *reinterpret_cast<short8*>(Bst + (size_t)o * R2 + q * 8) = buf[q];
  }
}

// ---------- kernel 2: W_eff via MFMA: Wb = bf16(W + Bst @ Abt^T) ----------
__global__ __launch_bounds__(256) void k_weff_mfma(const ushort* __restrict__ Bst, // [2048][128]
                                                   const ushort* __restrict__ Abt, // [2048][128]
                                                   const float* __restrict__ W,    // [2048][2048]
                                                   ushort* __restrict__ Wb) {      // [2048][2048]
  __shared__ __align__(128) char sA[32768];  // Bst tile: 128 rows(o) x 256B
  __shared__ __align__(128) char sB[32768];  // Abt tile: 128 rows(d) x 256B
  int bid = blockIdx.x;
  int o0 = (bid >> 4) * 128;
  int d0 = (bid & 15) * 128;
  int tid = threadIdx.x, w = tid >> 6, l = tid & 63;

  int srow = w * 32 + (l >> 4);
  int scolb = (l & 15) * 16;
  #pragma unroll
  for (int j = 0; j < 8; ++j) {
    int row = srow + j * 4;
    int colb = scolb ^ ((row & 7) << 4);
    lds16((const char*)Bst + (size_t)(o0 + row) * 256 + colb, sA + w * 8192 + j * 1024);
    lds16((const char*)Abt + (size_t)(d0 + row) * 256 + colb, sB + w * 8192 + j * 1024);
  }
  __syncthreads();

  int wr = w >> 1, wc = w & 1;     // wave -> 64x64 out sub-tile
  int fr = l & 15;
  int fk16 = (l >> 4) * 16;
  int xm = (fr & 7) << 4;

  f32x4 acc[4][4];
  #pragma unroll
  for (int i = 0; i < 4; ++i)
    #pragma unroll
    for (int j = 0; j < 4; ++j) acc[i][j] = f32x4{0.f, 0.f, 0.f, 0.f};

  #pragma unroll
  for (int ks = 0; ks < 4; ++ks) {
    int kx = (ks * 64 + fk16) ^ xm;
    bf16x8 aF[4], bF[4];
    #pragma unroll
    for (int mi = 0; mi < 4; ++mi)
      aF[mi] = *reinterpret_cast<const bf16x8*>(sA + (wr * 64 + mi * 16 + fr) * 256 + kx);
    #pragma unroll
    for (int nj = 0; nj < 4; ++nj)
      bF[nj] = *reinterpret_cast<const bf16x8*>(sB + (wc * 64 + nj * 16 + fr) * 256 + kx);
    #pragma unroll
    for (int mi = 0; mi < 4; ++mi)
      #pragma unroll
      for (int nj = 0; nj < 4; ++nj)
        acc[mi][nj] = __builtin_amdgcn_mfma_f32_16x16x32_bf16(aF[mi], bF[nj], acc[mi][nj], 0, 0, 0);
  }

  int rr4 = (l >> 4) * 4;
  #pragma unroll
  for (int nj = 0; nj < 4; ++nj) {
    int col = d0 + wc * 64 + nj * 16 + fr;
    #pragma unroll
    for (int mi = 0; mi < 4; ++mi) {
      int row0 = o0 + wr * 64 + mi * 16 + rr4;
      #pragma unroll
      for (int r = 0; r < 4; ++r) {
        float v = acc[mi][nj][r] + W[(size_t)(row0 + r) * Ktot + col];
        Wb[(size_t)(row0 + r) * Ktot + col] = f2bf(v);
      }
    }
  }
}

// ---------- kernel 3: 256x256-tile 8-wave GEMM, depth-2 cross-tile pipeline ----------
// Ring-4 buffers, prefetch-2, counted vmcnt (2 in steady state — never 0).
// Per tile t: stage(t+2,p0/p1); read aHi(t); MFMA mi0-3 (hides the wait);
// vmcnt(2); barrier; stage(t+2,p2/p3); read tile t+1's bF/aLo; MFMA mi4-7.
// bCur/bNxt rotate via unroll-by-2 (static indexing, rule #20).
__global__ __launch_bounds__(512, 2) void k_gemm256(const ushort* __restrict__ Xb,
                                                    const ushort* __restrict__ Wb,
                                                    const float* __restrict__ bias,
                                                    float* __restrict__ out) {
  constexpr int BK = 32;
  constexpr int NT = Ktot / BK;           // 64
  constexpr int NTN = Ntot / 256;         // 8
  __shared__ __align__(128) char smem[4 * 32768];   // ring: 4 x (A 16KB + B 16KB)

  int nwg = gridDim.x;                    // 256, %8==0
  int orig = blockIdx.x;
  int wg = (orig & 7) * (nwg >> 3) + (orig >> 3);
  int mBase = (wg / NTN) * 256;
  int nBase = (wg % NTN) * 256;

  int tid = threadIdx.x;
  int w = tid >> 6, l = tid & 63;
  int wr = w >> 2, wc = w & 3;            // wave -> 128x64 output sub-tile

  int rowOff = tid >> 2;
  int cbS = ((tid & 3) * 16) ^ (((tid >> 3) & 3) << 4);
  const char* xbB = (const char*)Xb;
  const char* wbB = (const char*)Wb;
  const char* src[4];
  src[0] = xbB + (size_t)(mBase +       rowOff) * (Ktot * 2) + cbS;  // A rows 0-127
  src[1] = xbB + (size_t)(mBase + 128 + rowOff) * (Ktot * 2) + cbS;  // A rows 128-255
  src[2] = wbB + (size_t)(nBase +       rowOff) * (Ktot * 2) + cbS;  // B rows 0-127
  src[3] = wbB + (size_t)(nBase + 128 + rowOff) * (Ktot * 2) + cbS;  // B rows 128-255
  int waveB = w * 1024;

  auto stage = [&](int bufn, int which, int tt) {
    lds16(src[which] + (size_t)tt * 64, smem + bufn * 32768 + which * 8192 + waveB);
  };

  int fr = l & 15;
  int fkb = (l >> 4) * 16;
  int kx = fkb ^ (((fr >> 1) & 3) << 4);
  int aRd = (wr * 128 + fr) * 64 + kx;            // + mi*1024
  int bRd = 16384 + (wc * 64 + fr) * 64 + kx;     // + nj*1024

  f32x4 acc[8][4];
  #pragma unroll
  for (int i = 0; i < 8; ++i)
    #pragma unroll
    for (int j = 0; j < 4; ++j) acc[i][j] = f32x4{0.f, 0.f, 0.f, 0.f};

  bf16x8 aLo[4], aHi[4], bX[4], bY[4];

  // prologue: stage tiles 0,1; drain tile 0; prime tile-0 registers.
  #pragma unroll
  for (int q = 0; q < 4; ++q) stage(0, q, 0);
  #pragma unroll
  for (int q = 0; q < 4; ++q) stage(1, q, 1);
  asm volatile("s_waitcnt vmcnt(4)" ::: "memory");
  __syncthreads();
  #pragma unroll
  for (int nj = 0; nj < 4; ++nj)
    bX[nj] = *reinterpret_cast<const bf16x8*>(smem + bRd + nj * 1024);
  #pragma unroll
  for (int mi = 0; mi < 4; ++mi)
    aLo[mi] = *reinterpret_cast<const bf16x8*>(smem + aRd + mi * 1024);

  auto tile_body = [&](int t, bf16x8 (&bCur)[4], bf16x8 (&bNxt)[4]) {
    const char* buf  = smem + (t & 3) * 32768;
    const char* bufN = smem + ((t + 1) & 3) * 32768;
    const bool pref = (t + 2 < NT);
    const int bn = (t + 2) & 3;

    if (pref) { stage(bn, 0, t + 2); stage(bn, 1, t + 2); }
    #pragma unroll
    for (int mi = 0; mi < 4; ++mi)
      aHi[mi] = *reinterpret_cast<const bf16x8*>(buf + aRd + (4 + mi) * 1024);
    __builtin_amdgcn_s_setprio(1);
    #pragma unroll
    for (int mi = 0; mi < 4; ++mi)
      #pragma unroll
      for (int nj = 0; nj < 4; ++nj)
        acc[mi][nj] = __builtin_amdgcn_mfma_f32_16x16x32_bf16(aLo[mi], bCur[nj], acc[mi][nj], 0, 0, 0);
    __builtin_amdgcn_s_setprio(0);

    if (pref) asm volatile("s_waitcnt vmcnt(2)" ::: "memory");
    else      asm volatile("s_waitcnt vmcnt(0)" ::: "memory");
    __builtin_amdgcn_s_barrier();
    if (pref) { stage(bn, 2, t + 2); stage(bn, 3, t + 2); }

    if (t + 1 < NT) {
      #pragma unroll
      for (int nj = 0; nj < 4; ++nj)
        bNxt[nj] = *reinterpret_cast<const bf16x8*>(bufN + bRd + nj * 1024);
      #pragma unroll
      for (int mi = 0; mi < 4; ++mi)
        aLo[mi] = *reinterpret_cast<const bf16x8*>(bufN + aRd + mi * 1024);
    }
    __builtin_amdgcn_s_setprio(1);
    #pragma unroll
    for (int mi = 0; mi < 4; ++mi)
      #pragma unroll
      for (int nj = 0; nj < 4; ++nj)
        acc[4 + mi][nj] = __builtin_amdgcn_mfma_f32_16x16x32_bf16(aHi[mi], bCur[nj], acc[4 + mi][nj], 0, 0, 0);
    __builtin_amdgcn_s_setprio(0);
  };

  for (int t = 0; t < NT; t += 2) {
    tile_body(t,     bX, bY);
    tile_body(t + 1, bY, bX);
  }

  int rr = (l >> 4) * 4;
  #pragma unroll
  for (int nj = 0; nj < 4; ++nj) {
    int col = nBase + wc * 64 + nj * 16 + fr;
    float bb = bias[col];
    #pragma unroll
    for (int mi = 0; mi < 8; ++mi) {
      int row0 = mBase + wr * 128 + mi * 16 + rr;
      #pragma unroll
      for (int r = 0; r < 4; ++r)
        out[(size_t)(row0 + r) * Ntot + col] = acc[mi][nj][r] + bb;
    }
  }
}

extern "C" void kernel_launch(void* const* d_in, const int* in_sizes, int n_in,
                              void* d_out, int out_size, void* d_ws, size_t ws_size,
                              hipStream_t stream) {
  const float* x    = (const float*)d_in[0];
  const float* W    = (const float*)d_in[1];
  const float* bias = (const float*)d_in[2];
  const float* lA   = (const float*)d_in[3];
  const float* lB   = (const float*)d_in[4];
  const int*   mask = (const int*)d_in[5];
  float* out = (float*)d_out;

  ushort* xb  = (ushort*)d_ws;                      // [M][K]   bf16: 33.55 MB
  ushort* wb  = xb + (size_t)Mtot * Ktot;           // [N][K]   bf16:  8.39 MB
  ushort* abt = wb + (size_t)Ntot * Ktot;           // [K][128] bf16:  0.52 MB
  ushort* bst = abt + (size_t)Ktot * R2;            // [N][128] bf16:  0.52 MB

  k_prep<<<8192 + 8 + 8, 256, 0, stream>>>(x, xb, lA, lB, mask, abt, bst);
  k_weff_mfma<<<(Ntot / 128) * (Ktot / 128), 256, 0, stream>>>(bst, abt, W, wb);
  k_gemm256<<<(Mtot / 256) * (Ntot / 256), 512, 0, stream>>>(xb, wb, bias, out);
}